// Round 6
// baseline (506.228 us; speedup 1.0000x reference)
//
#include <hip/hip_runtime.h>

#define N_NODES 25000
#define N_EDGES 400000
#define IN_DIM 174
#define HID_DIM 128
#define OUT_DIM 64
#define MPAD 25088   // 196 * 128, GEMM M padded
#define BINCAP 64    // max degree capacity (Poisson mean 16)

#define NBLK 768         // == guaranteed co-resident blocks (launch_bounds(256,3) -> 3/CU)
#define G1_TILES 392     // 196 m-tiles x 2 n-tiles
#define BIN_CHUNKS 391   // x 1024 edges
#define P1_VB (G1_TILES + BIN_CHUNKS)
#define G2_TILES 392
#define P2_VB 6272       // MPAD/4 groups (covers padded h1 zero-fill)
#define P4_VB 6250       // N_NODES/4 groups

using u32 = unsigned int;
typedef __attribute__((ext_vector_type(8))) short s16x8;
typedef __attribute__((ext_vector_type(4))) float f32x4;
typedef __attribute__((ext_vector_type(4))) u32 u32x4;

// ---------- bf16 helpers (RNE) ----------
__device__ __forceinline__ float bflo(u32 u) { u32 t = u << 16; return __builtin_bit_cast(float, t); }
__device__ __forceinline__ float bfhi(u32 u) { u32 t = u & 0xffff0000u; return __builtin_bit_cast(float, t); }
__device__ __forceinline__ u32 f2b(float f) {
    u32 u = __builtin_bit_cast(u32, f);
    return (u + 0x7fffu + ((u >> 16) & 1u)) >> 16;
}
__device__ __forceinline__ u32 packbf2(float a, float b) { return f2b(a) | (f2b(b) << 16); }

__device__ __forceinline__ void gload_lds16(const void* g, void* l) {
    __builtin_amdgcn_global_load_lds(
        (const __attribute__((address_space(1))) u32*)g,
        (__attribute__((address_space(3))) u32*)l, 16, 0, 0);
}

// ---------- device-scope grid barrier (all NBLK blocks co-resident) ----------
__device__ __forceinline__ void gridbar(int* bar) {
    __syncthreads();
    if (threadIdx.x == 0) {
        __threadfence();  // release: write-back L2 so other XCDs see our writes
        __hip_atomic_fetch_add(bar, 1, __ATOMIC_RELEASE, __HIP_MEMORY_SCOPE_AGENT);
        while (__hip_atomic_load(bar, __ATOMIC_RELAXED, __HIP_MEMORY_SCOPE_AGENT) < NBLK)
            __builtin_amdgcn_s_sleep(8);
    }
    __syncthreads();
    __threadfence();      // acquire: invalidate stale L1/L2 before reading others' data
}

__global__ __launch_bounds__(256, 3) void mono_kernel(
    const float* __restrict__ x, const int* __restrict__ ei,
    const float* __restrict__ W1l, const float* __restrict__ b1,
    const float* __restrict__ W1r, const float* __restrict__ W2l,
    const float* __restrict__ b2, const float* __restrict__ W2r,
    float2* __restrict__ out,
    int* bar, int* degI, int* __restrict__ bins,
    ushort* __restrict__ y1n, ushort* __restrict__ y1r,
    ushort* __restrict__ h1, ushort* __restrict__ y2n, ushort* __restrict__ y2r) {
    __shared__ ushort As[128 * 32];
    __shared__ ushort Bs[128 * 32];
    const int bid = blockIdx.x, tid = threadIdx.x;
    const int lane = tid & 63, w = tid >> 6;
    const int arow = lane >> 2;          // gload_lds: 16 rows per 1KB wave-call
    const int achunk = (lane & 3) * 8;
    const int r4 = tid >> 2;             // reg-stage: row within 64-row half
    const int q  = tid & 3;              // 16B chunk (8 bf16) within 32-elem slab
    const int fr = lane & 15, fo = (lane >> 4) * 8;
    const int cr = (lane >> 4) * 4, cc = lane & 15;

    // ================= P1: gemm1 (x fp32 -> bf16 in-kernel, W1 converted in-kernel)
    // =================     + edge binning (independent work, same phase)
    for (int vb = bid; vb < P1_VB; vb += NBLK) {
        if (vb < G1_TILES) {
            const int gy = vb / 196, gx = vb - gy * 196;
            const int m0 = gx * 128, n0 = gy * 128;
            const int wmo = (w >> 1) * 64, wno = (w & 1) * 64;
            f32x4 acc[4][4] = {};
            for (int kk = 0; kk < 192; kk += 32) {
                #pragma unroll
                for (int it = 0; it < 2; ++it) {
                    int r = it * 64 + r4;
                    // A: x row m0+r, cols kk+q*8 .. +8
                    {
                        int gm = m0 + r;
                        u32x4 o;
                        #pragma unroll
                        for (int e = 0; e < 4; ++e) {
                            int col = kk + q * 8 + e * 2;
                            float2 v = make_float2(0.f, 0.f);
                            if (gm < N_NODES && col < IN_DIM)
                                v = *(const float2*)(x + (size_t)gm * IN_DIM + col);
                            o[e] = packbf2(v.x, v.y);
                        }
                        ((u32x4*)As)[r * 4 + q] = o;
                    }
                    // B: weight row n0+r (W1l rows 0..127, W1r rows 128..255)
                    {
                        int wr = n0 + r;
                        const float* src = (wr < 128) ? W1l + (size_t)wr * IN_DIM
                                                      : W1r + (size_t)(wr - 128) * IN_DIM;
                        u32x4 o;
                        #pragma unroll
                        for (int e = 0; e < 4; ++e) {
                            int col = kk + q * 8 + e * 2;
                            float2 v = make_float2(0.f, 0.f);
                            if (col < IN_DIM) v = *(const float2*)(src + col);
                            o[e] = packbf2(v.x, v.y);
                        }
                        ((u32x4*)Bs)[r * 4 + q] = o;
                    }
                }
                __syncthreads();
                s16x8 af[4], bf[4];
                #pragma unroll
                for (int i = 0; i < 4; ++i) {
                    af[i] = *(const s16x8*)&As[(wmo + i * 16 + fr) * 32 + fo];
                    bf[i] = *(const s16x8*)&Bs[(wno + i * 16 + fr) * 32 + fo];
                }
                #pragma unroll
                for (int i = 0; i < 4; ++i)
                    #pragma unroll
                    for (int j = 0; j < 4; ++j)
                        acc[i][j] = __builtin_amdgcn_mfma_f32_16x16x32_bf16(af[i], bf[j], acc[i][j], 0, 0, 0);
                __syncthreads();
            }
            #pragma unroll
            for (int i = 0; i < 4; ++i)
                #pragma unroll
                for (int r = 0; r < 4; ++r) {
                    int row = m0 + wmo + i * 16 + cr + r;
                    #pragma unroll
                    for (int j = 0; j < 4; ++j) {
                        int colg = n0 + wno + j * 16 + cc;
                        ushort* Cp = (colg < 128) ? y1n : y1r;
                        int c = colg & 127;
                        Cp[(size_t)row * 128 + c] = (ushort)f2b(acc[i][j][r]);
                    }
                }
        } else {
            // edge binning: chunk of 1024 edges
            int e4 = ((vb - G1_TILES) * 256 + tid) * 4;
            if (e4 < N_EDGES) {
                int4 s = *(const int4*)(ei + e4);
                int4 t = *(const int4*)(ei + N_EDGES + e4);
                int p0 = atomicAdd(&degI[t.x], 1);
                if (p0 < BINCAP) bins[t.x * BINCAP + p0] = s.x;
                int p1 = atomicAdd(&degI[t.y], 1);
                if (p1 < BINCAP) bins[t.y * BINCAP + p1] = s.y;
                int p2 = atomicAdd(&degI[t.z], 1);
                if (p2 < BINCAP) bins[t.z * BINCAP + p2] = s.z;
                int p3 = atomicAdd(&degI[t.w], 1);
                if (p3 < BINCAP) bins[t.w * BINCAP + p3] = s.w;
            }
        }
    }
    gridbar(bar + 0);

    // ================= P2: agg1  h1 = relu(mean_neigh(y1n) + y1r + b1) ==========
    for (int vb = bid; vb < P2_VB; vb += NBLK) {
        int n = vb * 4 + w;
        if (n >= N_NODES) {
            if (n < MPAD) ((u32*)h1)[(size_t)n * 64 + lane] = 0;  // clean padded rows
            continue;
        }
        int deg = degI[n];
        int d = min(deg, BINCAP);
        const int* bp = bins + n * BINCAP;
        const u32* y1nu = (const u32*)y1n;
        float a0 = 0.f, a1 = 0.f;
        int j = 0;
        for (; j + 8 <= d; j += 8) {
            int4 sa = *(const int4*)(bp + j);
            int4 sb = *(const int4*)(bp + j + 4);
            u32 u0 = y1nu[(size_t)sa.x * 64 + lane];
            u32 u1 = y1nu[(size_t)sa.y * 64 + lane];
            u32 u2 = y1nu[(size_t)sa.z * 64 + lane];
            u32 u3 = y1nu[(size_t)sa.w * 64 + lane];
            u32 u4 = y1nu[(size_t)sb.x * 64 + lane];
            u32 u5 = y1nu[(size_t)sb.y * 64 + lane];
            u32 u6 = y1nu[(size_t)sb.z * 64 + lane];
            u32 u7 = y1nu[(size_t)sb.w * 64 + lane];
            a0 += bflo(u0) + bflo(u1) + bflo(u2) + bflo(u3)
                + bflo(u4) + bflo(u5) + bflo(u6) + bflo(u7);
            a1 += bfhi(u0) + bfhi(u1) + bfhi(u2) + bfhi(u3)
                + bfhi(u4) + bfhi(u5) + bfhi(u6) + bfhi(u7);
        }
        if (j + 4 <= d) {
            int4 s4 = *(const int4*)(bp + j);
            u32 u0 = y1nu[(size_t)s4.x * 64 + lane];
            u32 u1 = y1nu[(size_t)s4.y * 64 + lane];
            u32 u2 = y1nu[(size_t)s4.z * 64 + lane];
            u32 u3 = y1nu[(size_t)s4.w * 64 + lane];
            a0 += bflo(u0) + bflo(u1) + bflo(u2) + bflo(u3);
            a1 += bfhi(u0) + bfhi(u1) + bfhi(u2) + bfhi(u3);
            j += 4;
        }
        for (; j < d; ++j) {
            int s = bp[j];
            u32 u = y1nu[(size_t)s * 64 + lane];
            a0 += bflo(u); a1 += bfhi(u);
        }
        float inv = 1.f / fmaxf((float)deg, 1.f);
        u32 ur = ((const u32*)y1r)[(size_t)n * 64 + lane];
        float2 bb = ((const float2*)b1)[lane];
        float v0 = fmaxf(a0 * inv + bflo(ur) + bb.x, 0.f);
        float v1 = fmaxf(a1 * inv + bfhi(ur) + bb.y, 0.f);
        ((u32*)h1)[(size_t)n * 64 + lane] = packbf2(v0, v1);
    }
    gridbar(bar + 1);

    // ================= P3: gemm2  y2 = h1 @ [W2l|W2r]^T (W2 converted in-kernel) =
    for (int vb = bid; vb < G2_TILES; vb += NBLK) {
        const int m0 = vb * 64;
        const int wmo = (w >> 1) * 32, wno = (w & 1) * 64;
        f32x4 acc[2][4] = {};
        for (int kk = 0; kk < 128; kk += 32) {
            // A: h1 bf16 via async global->LDS (64 rows)
            {
                int r = w * 16;
                gload_lds16(h1 + (size_t)(m0 + r + arow) * 128 + kk + achunk, &As[r * 32]);
            }
            // B: W2 rows 0..127 (W2l 0..63, W2r 64..127), fp32 -> bf16
            #pragma unroll
            for (int it = 0; it < 2; ++it) {
                int r = it * 64 + r4;
                const float* src = (r < 64) ? W2l + (size_t)r * HID_DIM
                                            : W2r + (size_t)(r - 64) * HID_DIM;
                u32x4 o;
                #pragma unroll
                for (int e = 0; e < 4; ++e) {
                    int col = kk + q * 8 + e * 2;
                    float2 v = *(const float2*)(src + col);
                    o[e] = packbf2(v.x, v.y);
                }
                ((u32x4*)Bs)[r * 4 + q] = o;
            }
            __syncthreads();
            s16x8 af[2], bf[4];
            #pragma unroll
            for (int i = 0; i < 2; ++i)
                af[i] = *(const s16x8*)&As[(wmo + i * 16 + fr) * 32 + fo];
            #pragma unroll
            for (int j = 0; j < 4; ++j)
                bf[j] = *(const s16x8*)&Bs[(wno + j * 16 + fr) * 32 + fo];
            #pragma unroll
            for (int i = 0; i < 2; ++i)
                #pragma unroll
                for (int j = 0; j < 4; ++j)
                    acc[i][j] = __builtin_amdgcn_mfma_f32_16x16x32_bf16(af[i], bf[j], acc[i][j], 0, 0, 0);
            __syncthreads();
        }
        #pragma unroll
        for (int i = 0; i < 2; ++i)
            #pragma unroll
            for (int r = 0; r < 4; ++r) {
                int row = m0 + wmo + i * 16 + cr + r;
                #pragma unroll
                for (int j = 0; j < 4; ++j) {
                    int colg = wno + j * 16 + cc;
                    ushort* Cp = (colg < 64) ? y2n : y2r;
                    int c = colg & 63;
                    Cp[(size_t)row * 64 + c] = (ushort)f2b(acc[i][j][r]);
                }
            }
    }
    gridbar(bar + 2);

    // ================= P4: agg2  out = mean_neigh(y2n) + y2r + b2 (fp32) =========
    for (int vb = bid; vb < P4_VB; vb += NBLK) {
        int n = vb * 4 + w;
        if (n >= N_NODES) continue;
        int half = lane >> 5, dd = lane & 31;
        int deg = degI[n];
        int d = min(deg, BINCAP);
        const int* bp = bins + n * BINCAP;
        const u32* y2nu = (const u32*)y2n;
        float a0 = 0.f, a1 = 0.f;
        int j = 0;
        for (; j + 8 <= d; j += 8) {
            int s0 = bp[j + half],     s1 = bp[j + 2 + half];
            int s2 = bp[j + 4 + half], s3 = bp[j + 6 + half];
            u32 u0 = y2nu[(size_t)s0 * 32 + dd];
            u32 u1 = y2nu[(size_t)s1 * 32 + dd];
            u32 u2 = y2nu[(size_t)s2 * 32 + dd];
            u32 u3 = y2nu[(size_t)s3 * 32 + dd];
            a0 += bflo(u0) + bflo(u1) + bflo(u2) + bflo(u3);
            a1 += bfhi(u0) + bfhi(u1) + bfhi(u2) + bfhi(u3);
        }
        if (j + 4 <= d) {
            int s0 = bp[j + half], s1 = bp[j + 2 + half];
            u32 u0 = y2nu[(size_t)s0 * 32 + dd];
            u32 u1 = y2nu[(size_t)s1 * 32 + dd];
            a0 += bflo(u0) + bflo(u1);
            a1 += bfhi(u0) + bfhi(u1);
            j += 4;
        }
        if (j + 2 <= d) {
            int s = bp[j + half];
            u32 u = y2nu[(size_t)s * 32 + dd];
            a0 += bflo(u); a1 += bfhi(u);
            j += 2;
        }
        if (j < d && half == 0) {
            int s = bp[j];
            u32 u = y2nu[(size_t)s * 32 + dd];
            a0 += bflo(u); a1 += bfhi(u);
        }
        a0 += __shfl_xor(a0, 32, 64);
        a1 += __shfl_xor(a1, 32, 64);
        if (half == 0) {
            float inv = 1.f / fmaxf((float)deg, 1.f);
            u32 ur = ((const u32*)y2r)[(size_t)n * 32 + dd];
            float2 bb = ((const float2*)b2)[dd];
            float2 o;
            o.x = a0 * inv + bflo(ur) + bb.x;
            o.y = a1 * inv + bfhi(ur) + bb.y;
            out[(size_t)n * 32 + dd] = o;
        }
    }
}

// ---------------- launch ----------------

extern "C" void kernel_launch(void* const* d_in, const int* in_sizes, int n_in,
                              void* d_out, int out_size, void* d_ws, size_t ws_size,
                              hipStream_t stream) {
    const float* x   = (const float*)d_in[0];
    const int*   ei  = (const int*)d_in[1];
    const float* W1l = (const float*)d_in[2];
    const float* b1  = (const float*)d_in[3];
    const float* W1r = (const float*)d_in[4];
    const float* W2l = (const float*)d_in[5];
    const float* b2  = (const float*)d_in[6];
    const float* W2r = (const float*)d_in[7];

    char* wp = (char*)d_ws;
    auto alloc = [&](size_t bytes) -> char* {
        char* p = wp;
        wp += (bytes + 255) & ~(size_t)255;
        return p;
    };
    // bar + degI contiguous so one memset covers both
    int* bar  = (int*)alloc((size_t)(4 + N_NODES) * 4);
    int* degI = bar + 4;
    int* bins = (int*)alloc((size_t)N_NODES * BINCAP * 4);
    ushort* y1n = (ushort*)alloc((size_t)MPAD * 128 * 2);
    ushort* y1r = (ushort*)alloc((size_t)MPAD * 128 * 2);
    ushort* h1  = (ushort*)alloc((size_t)MPAD * 128 * 2);
    ushort* y2n = (ushort*)alloc((size_t)MPAD * 64 * 2);
    ushort* y2r = (ushort*)alloc((size_t)MPAD * 64 * 2);

    hipMemsetAsync(bar, 0, (size_t)(4 + N_NODES) * 4, stream);
    mono_kernel<<<NBLK, 256, 0, stream>>>(
        x, ei, W1l, b1, W1r, W2l, b2, W2r, (float2*)d_out,
        bar, degI, bins, y1n, y1r, h1, y2n, y2r);
}

// Round 7
// 85.418 us; speedup vs baseline: 5.9265x; 5.9265x over previous
//
#include <hip/hip_runtime.h>

#define N_NODES 25000
#define N_EDGES 400000
#define IN_DIM 174
#define HID_DIM 128
#define OUT_DIM 64
#define MPAD 25088   // 196 * 128, GEMM M padded
#define BINCAP 64    // max degree capacity (Poisson mean 16)

using u32 = unsigned int;
typedef __attribute__((ext_vector_type(8))) short s16x8;
typedef __attribute__((ext_vector_type(4))) float f32x4;
typedef __attribute__((ext_vector_type(4))) u32 u32x4;

// ---------- bf16 helpers (RNE) ----------
__device__ __forceinline__ float bflo(u32 u) { u32 t = u << 16; return __builtin_bit_cast(float, t); }
__device__ __forceinline__ float bfhi(u32 u) { u32 t = u & 0xffff0000u; return __builtin_bit_cast(float, t); }
__device__ __forceinline__ u32 f2b(float f) {
    u32 u = __builtin_bit_cast(u32, f);
    return (u + 0x7fffu + ((u >> 16) & 1u)) >> 16;
}
__device__ __forceinline__ u32 packbf2(float a, float b) { return f2b(a) | (f2b(b) << 16); }

__device__ __forceinline__ void gload_lds16(const void* g, void* l) {
    __builtin_amdgcn_global_load_lds(
        (const __attribute__((address_space(1))) u32*)g,
        (__attribute__((address_space(3))) u32*)l, 16, 0, 0);
}

// ---------------- gemm1 (x fp32 -> bf16 + W1 fp32 -> bf16 in-kernel) + edge binning ---
// gemm: C[m][n] = sum_k x_bf16[m][k] * W1_bf16[n][k], K=192 (zero-padded from 174).
// blocks [0,392): gemm tiles.  blocks [392,783): edge binning, 4 edges/thread.
#define G1_GEMM_BLOCKS 392
#define G1_EDGE_BLOCKS ((N_EDGES / 4 + 255) / 256)

__global__ __launch_bounds__(256) void gemm1_fused_kernel(
    const float* __restrict__ x,
    const float* __restrict__ W1l, const float* __restrict__ W1r,
    ushort* __restrict__ y1n, ushort* __restrict__ y1r,
    const int* __restrict__ ei, int* __restrict__ degI, int* __restrict__ bins) {
    const int bid = blockIdx.x;
    const int tid = threadIdx.x;

    if (bid >= G1_GEMM_BLOCKS) {
        // ---- edge binning ----
        int e4 = ((bid - G1_GEMM_BLOCKS) * 256 + tid) * 4;
        if (e4 < N_EDGES) {  // N_EDGES % 4 == 0
            int4 s = *(const int4*)(ei + e4);
            int4 t = *(const int4*)(ei + N_EDGES + e4);
            int p0 = atomicAdd(&degI[t.x], 1);
            if (p0 < BINCAP) bins[t.x * BINCAP + p0] = s.x;
            int p1 = atomicAdd(&degI[t.y], 1);
            if (p1 < BINCAP) bins[t.y * BINCAP + p1] = s.y;
            int p2 = atomicAdd(&degI[t.z], 1);
            if (p2 < BINCAP) bins[t.z * BINCAP + p2] = s.z;
            int p3 = atomicAdd(&degI[t.w], 1);
            if (p3 < BINCAP) bins[t.w * BINCAP + p3] = s.w;
        }
        return;
    }

    // ---- gemm tile ----
    __shared__ ushort As[128 * 32];
    __shared__ ushort Bs[128 * 32];
    const int lane = tid & 63, w = tid >> 6;
    const int gy = bid / 196, gx = bid - gy * 196;
    const int m0 = gx * 128, n0 = gy * 128;
    const int wmo = (w >> 1) * 64, wno = (w & 1) * 64;
    const int r4 = tid >> 2;             // reg-stage: row within 64-row half
    const int q  = tid & 3;              // 16B chunk (8 bf16) within 32-elem slab
    const int fr = lane & 15, fo = (lane >> 4) * 8;

    f32x4 acc[4][4] = {};

    for (int kk = 0; kk < 192; kk += 32) {
        #pragma unroll
        for (int it = 0; it < 2; ++it) {
            int r = it * 64 + r4;
            // A: x row m0+r, fp32 -> bf16
            {
                int gm = m0 + r;
                u32x4 o;
                #pragma unroll
                for (int e = 0; e < 4; ++e) {
                    int col = kk + q * 8 + e * 2;
                    float2 v = make_float2(0.f, 0.f);
                    if (gm < N_NODES && col < IN_DIM)
                        v = *(const float2*)(x + (size_t)gm * IN_DIM + col);
                    o[e] = packbf2(v.x, v.y);
                }
                ((u32x4*)As)[r * 4 + q] = o;
            }
            // B: W1 row n0+r (W1l rows 0..127, W1r rows 128..255), fp32 -> bf16
            {
                int wr = n0 + r;
                const float* src = (wr < 128) ? W1l + (size_t)wr * IN_DIM
                                              : W1r + (size_t)(wr - 128) * IN_DIM;
                u32x4 o;
                #pragma unroll
                for (int e = 0; e < 4; ++e) {
                    int col = kk + q * 8 + e * 2;
                    float2 v = make_float2(0.f, 0.f);
                    if (col < IN_DIM) v = *(const float2*)(src + col);
                    o[e] = packbf2(v.x, v.y);
                }
                ((u32x4*)Bs)[r * 4 + q] = o;
            }
        }
        __syncthreads();
        s16x8 af[4], bf[4];
        #pragma unroll
        for (int i = 0; i < 4; ++i) {
            af[i] = *(const s16x8*)&As[(wmo + i * 16 + fr) * 32 + fo];
            bf[i] = *(const s16x8*)&Bs[(wno + i * 16 + fr) * 32 + fo];
        }
        #pragma unroll
        for (int i = 0; i < 4; ++i)
            #pragma unroll
            for (int j = 0; j < 4; ++j)
                acc[i][j] = __builtin_amdgcn_mfma_f32_16x16x32_bf16(af[i], bf[j], acc[i][j], 0, 0, 0);
        __syncthreads();
    }

    const int cr = (lane >> 4) * 4, cc = lane & 15;
    #pragma unroll
    for (int i = 0; i < 4; ++i)
        #pragma unroll
        for (int r = 0; r < 4; ++r) {
            int row = m0 + wmo + i * 16 + cr + r;
            #pragma unroll
            for (int j = 0; j < 4; ++j) {
                int colg = n0 + wno + j * 16 + cc;
                ushort* Cp = (colg < 128) ? y1n : y1r;
                int c = colg & 127;
                Cp[(size_t)row * 128 + c] = (ushort)f2b(acc[i][j][r]);
            }
        }
}

// ---------------- gemm2: A = h1 bf16 (gload_lds), B = W2 fp32 -> bf16 in-kernel ------
// BM=64, K=128, N=128 (W2l rows 0..63 -> y2n, W2r rows 64..127 -> y2r). grid 392.
__global__ __launch_bounds__(256) void gemm2_kernel(
    const ushort* __restrict__ h1,
    const float* __restrict__ W2l, const float* __restrict__ W2r,
    ushort* __restrict__ y2n, ushort* __restrict__ y2r) {
    __shared__ ushort As[64 * 32];
    __shared__ ushort Bs[128 * 32];
    const int tid = threadIdx.x;
    const int lane = tid & 63, w = tid >> 6;
    const int m0 = blockIdx.x * 64;
    const int wmo = (w >> 1) * 32, wno = (w & 1) * 64;
    const int arow = lane >> 2;
    const int achunk = (lane & 3) * 8;
    const int r4 = tid >> 2;
    const int q  = tid & 3;
    const int fr = lane & 15, fo = (lane >> 4) * 8;

    f32x4 acc[2][4] = {};

    for (int kk = 0; kk < 128; kk += 32) {
        // A: h1 bf16 via async global->LDS (64 rows; padded h1 rows are finite garbage,
        // never read into outputs downstream)
        {
            int r = w * 16;
            gload_lds16(h1 + (size_t)(m0 + r + arow) * 128 + kk + achunk, &As[r * 32]);
        }
        // B: W2 rows 0..127 (W2l 0..63, W2r 64..127), fp32 -> bf16 (cols always < 128)
        #pragma unroll
        for (int it = 0; it < 2; ++it) {
            int r = it * 64 + r4;
            const float* src = (r < 64) ? W2l + (size_t)r * HID_DIM
                                        : W2r + (size_t)(r - 64) * HID_DIM;
            u32x4 o;
            #pragma unroll
            for (int e = 0; e < 4; ++e) {
                int col = kk + q * 8 + e * 2;
                float2 v = *(const float2*)(src + col);
                o[e] = packbf2(v.x, v.y);
            }
            ((u32x4*)Bs)[r * 4 + q] = o;
        }
        __syncthreads();
        s16x8 af[2], bf[4];
        #pragma unroll
        for (int i = 0; i < 2; ++i)
            af[i] = *(const s16x8*)&As[(wmo + i * 16 + fr) * 32 + fo];
        #pragma unroll
        for (int j = 0; j < 4; ++j)
            bf[j] = *(const s16x8*)&Bs[(wno + j * 16 + fr) * 32 + fo];
        #pragma unroll
        for (int i = 0; i < 2; ++i)
            #pragma unroll
            for (int j = 0; j < 4; ++j)
                acc[i][j] = __builtin_amdgcn_mfma_f32_16x16x32_bf16(af[i], bf[j], acc[i][j], 0, 0, 0);
        __syncthreads();
    }

    const int cr = (lane >> 4) * 4, cc = lane & 15;
    #pragma unroll
    for (int i = 0; i < 2; ++i)
        #pragma unroll
        for (int r = 0; r < 4; ++r) {
            int row = m0 + wmo + i * 16 + cr + r;
            #pragma unroll
            for (int j = 0; j < 4; ++j) {
                int colg = wno + j * 16 + cc;
                ushort* Cp = (colg < 64) ? y2n : y2r;
                int c = colg & 63;
                Cp[(size_t)row * 64 + c] = (ushort)f2b(acc[i][j][r]);
            }
        }
}

// ---------------- aggregation epilogues (binned, 8x unrolled gathers) ----------------
__global__ __launch_bounds__(256) void agg1_kernel(const u32* __restrict__ y1n,
                                                   const u32* __restrict__ y1r,
                                                   const int* __restrict__ degI,
                                                   const int* __restrict__ bins,
                                                   const float* __restrict__ b1,
                                                   u32* __restrict__ h1) {
    int w = threadIdx.x >> 6, lane = threadIdx.x & 63;
    int n = blockIdx.x * 4 + w;
    if (n >= N_NODES) return;
    int deg = degI[n];
    int d = min(deg, BINCAP);
    const int* bp = bins + n * BINCAP;
    float a0 = 0.f, a1 = 0.f;
    int j = 0;
    for (; j + 8 <= d; j += 8) {
        int4 sa = *(const int4*)(bp + j);
        int4 sb = *(const int4*)(bp + j + 4);
        u32 u0 = y1n[(size_t)sa.x * 64 + lane];
        u32 u1 = y1n[(size_t)sa.y * 64 + lane];
        u32 u2 = y1n[(size_t)sa.z * 64 + lane];
        u32 u3 = y1n[(size_t)sa.w * 64 + lane];
        u32 u4 = y1n[(size_t)sb.x * 64 + lane];
        u32 u5 = y1n[(size_t)sb.y * 64 + lane];
        u32 u6 = y1n[(size_t)sb.z * 64 + lane];
        u32 u7 = y1n[(size_t)sb.w * 64 + lane];
        a0 += bflo(u0) + bflo(u1) + bflo(u2) + bflo(u3)
            + bflo(u4) + bflo(u5) + bflo(u6) + bflo(u7);
        a1 += bfhi(u0) + bfhi(u1) + bfhi(u2) + bfhi(u3)
            + bfhi(u4) + bfhi(u5) + bfhi(u6) + bfhi(u7);
    }
    if (j + 4 <= d) {
        int4 s4 = *(const int4*)(bp + j);
        u32 u0 = y1n[(size_t)s4.x * 64 + lane];
        u32 u1 = y1n[(size_t)s4.y * 64 + lane];
        u32 u2 = y1n[(size_t)s4.z * 64 + lane];
        u32 u3 = y1n[(size_t)s4.w * 64 + lane];
        a0 += bflo(u0) + bflo(u1) + bflo(u2) + bflo(u3);
        a1 += bfhi(u0) + bfhi(u1) + bfhi(u2) + bfhi(u3);
        j += 4;
    }
    for (; j < d; ++j) {
        int s = bp[j];
        u32 u = y1n[(size_t)s * 64 + lane];
        a0 += bflo(u); a1 += bfhi(u);
    }
    float inv = 1.f / fmaxf((float)deg, 1.f);
    u32 ur = y1r[(size_t)n * 64 + lane];
    float2 bb = ((const float2*)b1)[lane];
    float v0 = fmaxf(a0 * inv + bflo(ur) + bb.x, 0.f);
    float v1 = fmaxf(a1 * inv + bfhi(ur) + bb.y, 0.f);
    h1[(size_t)n * 64 + lane] = packbf2(v0, v1);
}

__global__ __launch_bounds__(256) void agg2_kernel(const u32* __restrict__ y2n,
                                                   const u32* __restrict__ y2r,
                                                   const int* __restrict__ degI,
                                                   const int* __restrict__ bins,
                                                   const float* __restrict__ b2,
                                                   float2* __restrict__ out) {
    int w = threadIdx.x >> 6, lane = threadIdx.x & 63;
    int half = lane >> 5, dd = lane & 31;
    int n = blockIdx.x * 4 + w;
    if (n >= N_NODES) return;
    int deg = degI[n];
    int d = min(deg, BINCAP);
    const int* bp = bins + n * BINCAP;
    float a0 = 0.f, a1 = 0.f;
    int j = 0;
    for (; j + 8 <= d; j += 8) {
        int s0 = bp[j + half],     s1 = bp[j + 2 + half];
        int s2 = bp[j + 4 + half], s3 = bp[j + 6 + half];
        u32 u0 = y2n[(size_t)s0 * 32 + dd];
        u32 u1 = y2n[(size_t)s1 * 32 + dd];
        u32 u2 = y2n[(size_t)s2 * 32 + dd];
        u32 u3 = y2n[(size_t)s3 * 32 + dd];
        a0 += bflo(u0) + bflo(u1) + bflo(u2) + bflo(u3);
        a1 += bfhi(u0) + bfhi(u1) + bfhi(u2) + bfhi(u3);
    }
    if (j + 4 <= d) {
        int s0 = bp[j + half], s1 = bp[j + 2 + half];
        u32 u0 = y2n[(size_t)s0 * 32 + dd];
        u32 u1 = y2n[(size_t)s1 * 32 + dd];
        a0 += bflo(u0) + bflo(u1);
        a1 += bfhi(u0) + bfhi(u1);
        j += 4;
    }
    if (j + 2 <= d) {
        int s = bp[j + half];
        u32 u = y2n[(size_t)s * 32 + dd];
        a0 += bflo(u); a1 += bfhi(u);
        j += 2;
    }
    if (j < d && half == 0) {
        int s = bp[j];
        u32 u = y2n[(size_t)s * 32 + dd];
        a0 += bflo(u); a1 += bfhi(u);
    }
    a0 += __shfl_xor(a0, 32, 64);
    a1 += __shfl_xor(a1, 32, 64);
    if (half == 0) {
        float inv = 1.f / fmaxf((float)deg, 1.f);
        u32 ur = y2r[(size_t)n * 32 + dd];
        float2 bb = ((const float2*)b2)[dd];
        float2 o;
        o.x = a0 * inv + bflo(ur) + bb.x;
        o.y = a1 * inv + bfhi(ur) + bb.y;
        out[(size_t)n * 32 + dd] = o;
    }
}

// ---------------- launch ----------------

extern "C" void kernel_launch(void* const* d_in, const int* in_sizes, int n_in,
                              void* d_out, int out_size, void* d_ws, size_t ws_size,
                              hipStream_t stream) {
    const float* x   = (const float*)d_in[0];
    const int*   ei  = (const int*)d_in[1];
    const float* W1l = (const float*)d_in[2];
    const float* b1  = (const float*)d_in[3];
    const float* W1r = (const float*)d_in[4];
    const float* W2l = (const float*)d_in[5];
    const float* b2  = (const float*)d_in[6];
    const float* W2r = (const float*)d_in[7];

    char* wp = (char*)d_ws;
    auto alloc = [&](size_t bytes) -> char* {
        char* p = wp;
        wp += (bytes + 255) & ~(size_t)255;
        return p;
    };
    int* degI = (int*)alloc((size_t)N_NODES * 4);
    int* bins = (int*)alloc((size_t)N_NODES * BINCAP * 4);
    ushort* y1n = (ushort*)alloc((size_t)MPAD * 128 * 2);
    ushort* y1r = (ushort*)alloc((size_t)MPAD * 128 * 2);
    ushort* h1  = (ushort*)alloc((size_t)MPAD * 128 * 2);
    ushort* y2n = (ushort*)alloc((size_t)MPAD * 64 * 2);
    ushort* y2r = (ushort*)alloc((size_t)MPAD * 64 * 2);

    hipMemsetAsync(degI, 0, (size_t)N_NODES * 4, stream);
    gemm1_fused_kernel<<<G1_GEMM_BLOCKS + G1_EDGE_BLOCKS, 256, 0, stream>>>(
        x, W1l, W1r, (ushort*)y1n, (ushort*)y1r, ei, degI, bins);
    agg1_kernel<<<(N_NODES + 3) / 4, 256, 0, stream>>>(
        (const u32*)y1n, (const u32*)y1r, degI, bins, b1, (u32*)h1);
    gemm2_kernel<<<392, 256, 0, stream>>>(h1, W2l, W2r, y2n, y2r);
    agg2_kernel<<<(N_NODES + 3) / 4, 256, 0, stream>>>(
        (const u32*)y2n, (const u32*)y2r, degI, bins, b2, (float2*)d_out);
}